// Round 5
// baseline (501.648 us; speedup 1.0000x reference)
//
#include <hip/hip_runtime.h>
#include <hip/hip_fp16.h>

#define H_ 1024
#define W_ 1024
#define RAD 30
#define EPSF 1.3f
#define SH 16             // output rows per block
#define NYS (H_ / SH)     // 64 y-segments
#define NXS 2             // x-segments
#define XOUT 512          // output px per x-seg
#define SPAN 576          // XOUT + 2*32 halo (30 rounded up)
#define NT 192            // threads per block (3 waves), 3 px/thread
#define NXCD 8

// padded LDS index: breaks stride bank patterns on prefix reads
__device__ __forceinline__ int padidx(int i) { return i + (i >> 3); }
#define PSZ (SPAN + (SPAN >> 3) + 1 + 4)   // padidx(576)=648 -> 653 w/ slack

__device__ __forceinline__ float wscan(float v, int lane) {
#pragma unroll
    for (int d = 1; d < 64; d <<= 1) {
        const float t = __shfl_up(v, d, 64);
        if (lane >= d) v += t;
    }
    return v;
}

// ---------------------------------------------------------------------------
// gf_ab: block = (plane, x-seg, 16-row y-seg). Vertical sliding sums of
// {R, I, R*I, R*R} in registers (3 px/thread over 576-px span incl. halo);
// per row an in-LDS prefix scan over the span gives 2D box sums; solve
// a = cov/(var+eps), b = mI - a*mR; write packed half2(a,b).
// ---------------------------------------------------------------------------
__global__ __launch_bounds__(NT, 6)
void gf_ab(const float* __restrict__ I, const float* __restrict__ R,
           long long in_off, int nb, __half2* __restrict__ AB)
{
    __shared__ float P[4][PSZ];
    __shared__ float wt[4][3];

    // bijective XCD swizzle (nb % 8 == 0 by construction)
    const int q = nb / NXCD;
    const int bid = (int)blockIdx.x;
    const int sbid = (bid % NXCD) * q + bid / NXCD;
    const int pl  = sbid / (NXS * NYS);
    const int rem = sbid % (NXS * NYS);
    const int xs  = rem / NYS;
    const int ys  = rem % NYS;          // y fastest: neighbors share halo in L2

    const int tid = threadIdx.x;
    const int lane = tid & 63, wid = tid >> 6;
    const int e0 = tid * 3;             // first owned span element
    const int X0 = xs * XOUT;
    const int y0 = ys * SH;
    const long long pb = (long long)pl * (long long)(H_ * W_);
    const long long ib = in_off + pb;

    int gx[3]; bool vx[3];
#pragma unroll
    for (int j = 0; j < 3; ++j) {
        gx[j] = X0 - 32 + e0 + j;
        vx[j] = (gx[j] >= 0) && (gx[j] < W_);
    }

    float s[4][3];
#pragma unroll
    for (int f = 0; f < 4; ++f)
#pragma unroll
        for (int j = 0; j < 3; ++j) s[f][j] = 0.0f;

    // warm-up rows [y0-RAD, y0+RAD] clipped
    {
        const int wlo = max(0, y0 - RAD), whi = min(H_ - 1, y0 + RAD);
        for (int yy = wlo; yy <= whi; ++yy) {
            const long long ro = ib + (long long)yy * W_;
#pragma unroll
            for (int j = 0; j < 3; ++j) {
                if (vx[j]) {
                    const float r = R[ro + gx[j]], i = I[ro + gx[j]];
                    s[0][j] += r; s[1][j] += i;
                    s[2][j] += r * i; s[3][j] += r * r;
                }
            }
        }
    }

    for (int y = y0; y < y0 + SH; ++y) {
        // per-field: local 3-scan, wave scan, stash wave totals
        float ps[4][3], tot[4], wsc[4];
#pragma unroll
        for (int f = 0; f < 4; ++f) {
            ps[f][0] = s[f][0];
            ps[f][1] = ps[f][0] + s[f][1];
            ps[f][2] = ps[f][1] + s[f][2];
            tot[f] = ps[f][2];
            wsc[f] = wscan(tot[f], lane);
            if (lane == 63) wt[f][wid] = wsc[f];
        }
        __syncthreads();   // b1: wt visible

#pragma unroll
        for (int f = 0; f < 4; ++f) {
            float woff = 0.0f;
#pragma unroll
            for (int w = 0; w < 3; ++w)
                if (w < wid) woff += wt[f][w];
            const float ex = woff + wsc[f] - tot[f];  // exclusive prefix at e0
#pragma unroll
            for (int j = 0; j < 3; ++j)
                P[f][padidx(e0 + 1 + j)] = ex + ps[f][j];
        }
        if (tid == 0) {
#pragma unroll
            for (int f = 0; f < 4; ++f) P[f][0] = 0.0f;   // padidx(0)==0
        }
        __syncthreads();   // b2: P visible

        const float icy = 1.0f / (float)(min(y + RAD, H_ - 1) - max(y - RAD, 0) + 1);
#pragma unroll
        for (int j = 0; j < 3; ++j) {
            const int e = e0 + j;
            if (e >= 32 && e < 32 + XOUT) {
                const int hi = padidx(e + RAD + 1);   // <= padidx(574)
                const int lo = padidx(e - RAD);
                const float SR = P[0][hi] - P[0][lo];
                const float SI = P[1][hi] - P[1][lo];
                const float SP = P[2][hi] - P[2][lo];
                const float SQ = P[3][hi] - P[3][lo];
                const int x = gx[j];
                const float cntx = (float)(min(x + RAD, W_ - 1) - max(x - RAD, 0) + 1);
                const float invN = icy / cntx;
                const float mR = SR * invN, mI = SI * invN;
                const float a = (SP * invN - mR * mI) / (SQ * invN - mR * mR + EPSF);
                const float b = mI - a * mR;
                AB[pb + (long long)y * W_ + x] = __floats2half2_rn(a, b);
            }
        }

        // slide vertical window
        const int ya = y + RAD + 1, yb = y - RAD;
        if (ya < H_) {
            const long long ro = ib + (long long)ya * W_;
#pragma unroll
            for (int j = 0; j < 3; ++j) {
                if (vx[j]) {
                    const float r = R[ro + gx[j]], i = I[ro + gx[j]];
                    s[0][j] += r; s[1][j] += i;
                    s[2][j] += r * i; s[3][j] += r * r;
                }
            }
        }
        if (yb >= 0) {
            const long long ro = ib + (long long)yb * W_;
#pragma unroll
            for (int j = 0; j < 3; ++j) {
                if (vx[j]) {
                    const float r = R[ro + gx[j]], i = I[ro + gx[j]];
                    s[0][j] -= r; s[1][j] -= i;
                    s[2][j] -= r * i; s[3][j] -= r * r;
                }
            }
        }
    }
}

// ---------------------------------------------------------------------------
// gf_cd: same structure over packed half2 {a,b}; out = mean_a * R + mean_b.
// ---------------------------------------------------------------------------
__global__ __launch_bounds__(NT, 6)
void gf_cd(const __half2* __restrict__ AB, const float* __restrict__ Rimg,
           long long in_off, int nb, float* __restrict__ out)
{
    __shared__ float P[2][PSZ];
    __shared__ float wt[2][3];

    const int q = nb / NXCD;
    const int bid = (int)blockIdx.x;
    const int sbid = (bid % NXCD) * q + bid / NXCD;
    const int pl  = sbid / (NXS * NYS);
    const int rem = sbid % (NXS * NYS);
    const int xs  = rem / NYS;
    const int ys  = rem % NYS;

    const int tid = threadIdx.x;
    const int lane = tid & 63, wid = tid >> 6;
    const int e0 = tid * 3;
    const int X0 = xs * XOUT;
    const int y0 = ys * SH;
    const long long pb = (long long)pl * (long long)(H_ * W_);
    const long long ib = in_off + pb;

    int gx[3]; bool vx[3];
#pragma unroll
    for (int j = 0; j < 3; ++j) {
        gx[j] = X0 - 32 + e0 + j;
        vx[j] = (gx[j] >= 0) && (gx[j] < W_);
    }

    float s[2][3];
#pragma unroll
    for (int f = 0; f < 2; ++f)
#pragma unroll
        for (int j = 0; j < 3; ++j) s[f][j] = 0.0f;

    {
        const int wlo = max(0, y0 - RAD), whi = min(H_ - 1, y0 + RAD);
        for (int yy = wlo; yy <= whi; ++yy) {
            const long long ro = pb + (long long)yy * W_;
#pragma unroll
            for (int j = 0; j < 3; ++j) {
                if (vx[j]) {
                    const float2 ab = __half22float2(AB[ro + gx[j]]);
                    s[0][j] += ab.x; s[1][j] += ab.y;
                }
            }
        }
    }

    for (int y = y0; y < y0 + SH; ++y) {
        float ps[2][3], tot[2], wsc[2];
#pragma unroll
        for (int f = 0; f < 2; ++f) {
            ps[f][0] = s[f][0];
            ps[f][1] = ps[f][0] + s[f][1];
            ps[f][2] = ps[f][1] + s[f][2];
            tot[f] = ps[f][2];
            wsc[f] = wscan(tot[f], lane);
            if (lane == 63) wt[f][wid] = wsc[f];
        }
        __syncthreads();   // b1

#pragma unroll
        for (int f = 0; f < 2; ++f) {
            float woff = 0.0f;
#pragma unroll
            for (int w = 0; w < 3; ++w)
                if (w < wid) woff += wt[f][w];
            const float ex = woff + wsc[f] - tot[f];
#pragma unroll
            for (int j = 0; j < 3; ++j)
                P[f][padidx(e0 + 1 + j)] = ex + ps[f][j];
        }
        if (tid == 0) { P[0][0] = 0.0f; P[1][0] = 0.0f; }
        __syncthreads();   // b2

        const float icy = 1.0f / (float)(min(y + RAD, H_ - 1) - max(y - RAD, 0) + 1);
#pragma unroll
        for (int j = 0; j < 3; ++j) {
            const int e = e0 + j;
            if (e >= 32 && e < 32 + XOUT) {
                const int hi = padidx(e + RAD + 1);
                const int lo = padidx(e - RAD);
                const float SA = P[0][hi] - P[0][lo];
                const float SB = P[1][hi] - P[1][lo];
                const int x = gx[j];
                const float cntx = (float)(min(x + RAD, W_ - 1) - max(x - RAD, 0) + 1);
                const float invN = icy / cntx;
                const long long og = ib + (long long)y * W_ + x;
                out[og] = (SA * invN) * Rimg[og] + SB * invN;
            }
        }

        const int ya = y + RAD + 1, yb = y - RAD;
        if (ya < H_) {
            const long long ro = pb + (long long)ya * W_;
#pragma unroll
            for (int j = 0; j < 3; ++j) {
                if (vx[j]) {
                    const float2 ab = __half22float2(AB[ro + gx[j]]);
                    s[0][j] += ab.x; s[1][j] += ab.y;
                }
            }
        }
        if (yb >= 0) {
            const long long ro = pb + (long long)yb * W_;
#pragma unroll
            for (int j = 0; j < 3; ++j) {
                if (vx[j]) {
                    const float2 ab = __half22float2(AB[ro + gx[j]]);
                    s[0][j] -= ab.x; s[1][j] -= ab.y;
                }
            }
        }
    }
}

// ---------------------------------------------------------------------------
extern "C" void kernel_launch(void* const* d_in, const int* in_sizes, int n_in,
                              void* d_out, int out_size, void* d_ws, size_t ws_size,
                              hipStream_t stream)
{
    const float* I = (const float*)d_in[0];   // image to filter
    const float* R = (const float*)d_in[1];   // guidance image
    float* out = (float*)d_out;

    const long long plane = (long long)H_ * W_;
    const int P_ = (int)(in_sizes[0] / plane);              // 24 planes
    const size_t ab_pb = (size_t)plane * sizeof(__half2);   // 4 MB/plane

    int CH = (int)(ws_size / ab_pb);
    if (CH > P_) CH = P_;
    if (CH < 1) CH = 1;

    __half2* AB = (__half2*)d_ws;

    for (int p0 = 0; p0 < P_; p0 += CH) {
        const int pc = (P_ - p0 < CH) ? (P_ - p0) : CH;
        const long long in_off = (long long)p0 * plane;
        const int nb = NXS * NYS * pc;   // 128*pc => % 8 == 0

        hipLaunchKernelGGL(gf_ab, dim3(nb), dim3(NT), 0, stream,
                           I, R, in_off, nb, AB);
        hipLaunchKernelGGL(gf_cd, dim3(nb), dim3(NT), 0, stream,
                           AB, R, in_off, nb, out);
    }
}

// Round 6
// 281.891 us; speedup vs baseline: 1.7796x; 1.7796x over previous
//
#include <hip/hip_runtime.h>
#include <hip/hip_fp16.h>

#define H_ 1024
#define W_ 1024
#define RAD 30
#define EPSF 1.3f
#define SH 32            // output rows per block
#define NSEG (H_ / SH)   // 32 y-segments
#define NT 512           // 8 waves; 2 px/thread over the full 1024-px row
#define NXCD 8

// padded LDS index: breaks stride bank patterns on prefix reads
__device__ __forceinline__ int padidx(int i) { return i + (i >> 3); }
#define PSZ (W_ + (W_ >> 3) + 1)   // padidx(1024)=1152 -> 1153

__device__ __forceinline__ float wscan(float v, int lane) {
#pragma unroll
    for (int d = 1; d < 64; d <<= 1) {
        const float t = __shfl_up(v, d, 64);
        if (lane >= d) v += t;
    }
    return v;
}

// ---------------------------------------------------------------------------
// gf_ab: block = (plane, 32-row segment), 512 threads, full-width row.
// Vertical sliding sums of {R, I, R*I, R*R} in registers (2 px/thread);
// per row an in-LDS prefix scan gives 2D box sums; solve a, b; write
// packed half2(a,b).
// ---------------------------------------------------------------------------
__global__ __launch_bounds__(NT, 6)
void gf_ab(const float* __restrict__ I, const float* __restrict__ R,
           long long in_off, int nb, __half2* __restrict__ AB)
{
    __shared__ float P[4][PSZ];
    __shared__ float wt[4][8];

    // bijective XCD swizzle (nb % 8 == 0): consecutive segs -> same XCD
    const int q = nb / NXCD;
    const int bid = (int)blockIdx.x;
    const int sbid = (bid % NXCD) * q + bid / NXCD;
    const int seg = sbid % NSEG;
    const int pl  = sbid / NSEG;

    const int tid = threadIdx.x;
    const int lane = tid & 63, wid = tid >> 6;
    const int x0 = tid * 2;
    const int y0 = seg * SH;
    const long long pb = (long long)pl * (long long)(H_ * W_);
    const long long ib = in_off + pb;

    float icx[2];
#pragma unroll
    for (int j = 0; j < 2; ++j) {
        const int x = x0 + j;
        icx[j] = 1.0f / (float)(min(x + RAD, W_ - 1) - max(x - RAD, 0) + 1);
    }

    float s[4][2];
#pragma unroll
    for (int f = 0; f < 4; ++f) { s[f][0] = 0.0f; s[f][1] = 0.0f; }

    // warm-up rows [y0-RAD, y0+RAD] clipped
    {
        const int wlo = max(0, y0 - RAD), whi = min(H_ - 1, y0 + RAD);
#pragma unroll 4
        for (int yy = wlo; yy <= whi; ++yy) {
            const float2 r2 = *(const float2*)(R + ib + (long long)yy * W_ + x0);
            const float2 i2 = *(const float2*)(I + ib + (long long)yy * W_ + x0);
            s[0][0] += r2.x; s[0][1] += r2.y;
            s[1][0] += i2.x; s[1][1] += i2.y;
            s[2][0] += r2.x * i2.x; s[2][1] += r2.y * i2.y;
            s[3][0] += r2.x * r2.x; s[3][1] += r2.y * r2.y;
        }
    }

    for (int y = y0; y < y0 + SH; ++y) {
        float ps[4][2], tot[4], wsc[4];
#pragma unroll
        for (int f = 0; f < 4; ++f) {
            ps[f][0] = s[f][0];
            ps[f][1] = ps[f][0] + s[f][1];
            tot[f] = ps[f][1];
            wsc[f] = wscan(tot[f], lane);
            if (lane == 63) wt[f][wid] = wsc[f];
        }
        __syncthreads();   // b1: wt visible

#pragma unroll
        for (int f = 0; f < 4; ++f) {
            float woff = 0.0f;
#pragma unroll
            for (int w = 0; w < 8; ++w)
                if (w < wid) woff += wt[f][w];
            const float ex = woff + wsc[f] - tot[f];  // exclusive prefix at x0
            P[f][padidx(x0 + 1)] = ex + ps[f][0];
            P[f][padidx(x0 + 2)] = ex + ps[f][1];
        }
        if (tid == 0) {
#pragma unroll
            for (int f = 0; f < 4; ++f) P[f][0] = 0.0f;   // padidx(0)==0
        }
        __syncthreads();   // b2: P visible

        const float icy = 1.0f / (float)(min(y + RAD, H_ - 1) - max(y - RAD, 0) + 1);
        __half2 hv[2];
#pragma unroll
        for (int j = 0; j < 2; ++j) {
            const int x = x0 + j;
            const int hi = padidx(min(x + RAD + 1, W_));
            const int lo = padidx(max(x - RAD, 0));
            const float SR = P[0][hi] - P[0][lo];
            const float SI = P[1][hi] - P[1][lo];
            const float SP = P[2][hi] - P[2][lo];
            const float SQ = P[3][hi] - P[3][lo];
            const float invN = icx[j] * icy;
            const float mR = SR * invN, mI = SI * invN;
            const float a = (SP * invN - mR * mI) / (SQ * invN - mR * mR + EPSF);
            const float b = mI - a * mR;
            hv[j] = __floats2half2_rn(a, b);
        }
        const long long ob = pb + (long long)y * W_ + x0;
        uint2 u;
        u.x = *(const unsigned*)&hv[0];
        u.y = *(const unsigned*)&hv[1];
        *(uint2*)(AB + ob) = u;   // 8B store of two half2

        // slide vertical window
        const int ya = y + RAD + 1, yb = y - RAD;
        if (ya < H_) {
            const float2 r2 = *(const float2*)(R + ib + (long long)ya * W_ + x0);
            const float2 i2 = *(const float2*)(I + ib + (long long)ya * W_ + x0);
            s[0][0] += r2.x; s[0][1] += r2.y;
            s[1][0] += i2.x; s[1][1] += i2.y;
            s[2][0] += r2.x * i2.x; s[2][1] += r2.y * i2.y;
            s[3][0] += r2.x * r2.x; s[3][1] += r2.y * r2.y;
        }
        if (yb >= 0) {
            const float2 r2 = *(const float2*)(R + ib + (long long)yb * W_ + x0);
            const float2 i2 = *(const float2*)(I + ib + (long long)yb * W_ + x0);
            s[0][0] -= r2.x; s[0][1] -= r2.y;
            s[1][0] -= i2.x; s[1][1] -= i2.y;
            s[2][0] -= r2.x * i2.x; s[2][1] -= r2.y * i2.y;
            s[3][0] -= r2.x * r2.x; s[3][1] -= r2.y * r2.y;
        }
    }
}

// ---------------------------------------------------------------------------
// gf_cd: same structure over packed half2 {a,b}; out = mean_a * R + mean_b.
// ---------------------------------------------------------------------------
__global__ __launch_bounds__(NT, 6)
void gf_cd(const __half2* __restrict__ AB, const float* __restrict__ Rimg,
           long long in_off, int nb, float* __restrict__ out)
{
    __shared__ float P[2][PSZ];
    __shared__ float wt[2][8];

    const int q = nb / NXCD;
    const int bid = (int)blockIdx.x;
    const int sbid = (bid % NXCD) * q + bid / NXCD;
    const int seg = sbid % NSEG;
    const int pl  = sbid / NSEG;

    const int tid = threadIdx.x;
    const int lane = tid & 63, wid = tid >> 6;
    const int x0 = tid * 2;
    const int y0 = seg * SH;
    const long long pb = (long long)pl * (long long)(H_ * W_);
    const long long ib = in_off + pb;

    float icx[2];
#pragma unroll
    for (int j = 0; j < 2; ++j) {
        const int x = x0 + j;
        icx[j] = 1.0f / (float)(min(x + RAD, W_ - 1) - max(x - RAD, 0) + 1);
    }

    float s[2][2];
    s[0][0] = s[0][1] = s[1][0] = s[1][1] = 0.0f;

    {
        const int wlo = max(0, y0 - RAD), whi = min(H_ - 1, y0 + RAD);
#pragma unroll 4
        for (int yy = wlo; yy <= whi; ++yy) {
            const uint2 u = *(const uint2*)(AB + pb + (long long)yy * W_ + x0);
            const float2 ab0 = __half22float2(*(const __half2*)&u.x);
            const float2 ab1 = __half22float2(*(const __half2*)&u.y);
            s[0][0] += ab0.x; s[1][0] += ab0.y;
            s[0][1] += ab1.x; s[1][1] += ab1.y;
        }
    }

    for (int y = y0; y < y0 + SH; ++y) {
        float ps[2][2], tot[2], wsc[2];
#pragma unroll
        for (int f = 0; f < 2; ++f) {
            ps[f][0] = s[f][0];
            ps[f][1] = ps[f][0] + s[f][1];
            tot[f] = ps[f][1];
            wsc[f] = wscan(tot[f], lane);
            if (lane == 63) wt[f][wid] = wsc[f];
        }
        __syncthreads();   // b1

#pragma unroll
        for (int f = 0; f < 2; ++f) {
            float woff = 0.0f;
#pragma unroll
            for (int w = 0; w < 8; ++w)
                if (w < wid) woff += wt[f][w];
            const float ex = woff + wsc[f] - tot[f];
            P[f][padidx(x0 + 1)] = ex + ps[f][0];
            P[f][padidx(x0 + 2)] = ex + ps[f][1];
        }
        if (tid == 0) { P[0][0] = 0.0f; P[1][0] = 0.0f; }
        __syncthreads();   // b2

        const float icy = 1.0f / (float)(min(y + RAD, H_ - 1) - max(y - RAD, 0) + 1);
        const long long og = ib + (long long)y * W_ + x0;
        const float2 r2 = *(const float2*)(Rimg + og);
        float ov[2];
        const float rv[2] = {r2.x, r2.y};
#pragma unroll
        for (int j = 0; j < 2; ++j) {
            const int x = x0 + j;
            const int hi = padidx(min(x + RAD + 1, W_));
            const int lo = padidx(max(x - RAD, 0));
            const float SA = P[0][hi] - P[0][lo];
            const float SB = P[1][hi] - P[1][lo];
            const float invN = icx[j] * icy;
            ov[j] = (SA * invN) * rv[j] + SB * invN;
        }
        *(float2*)(out + og) = make_float2(ov[0], ov[1]);

        const int ya = y + RAD + 1, yb = y - RAD;
        if (ya < H_) {
            const uint2 u = *(const uint2*)(AB + pb + (long long)ya * W_ + x0);
            const float2 ab0 = __half22float2(*(const __half2*)&u.x);
            const float2 ab1 = __half22float2(*(const __half2*)&u.y);
            s[0][0] += ab0.x; s[1][0] += ab0.y;
            s[0][1] += ab1.x; s[1][1] += ab1.y;
        }
        if (yb >= 0) {
            const uint2 u = *(const uint2*)(AB + pb + (long long)yb * W_ + x0);
            const float2 ab0 = __half22float2(*(const __half2*)&u.x);
            const float2 ab1 = __half22float2(*(const __half2*)&u.y);
            s[0][0] -= ab0.x; s[1][0] -= ab0.y;
            s[0][1] -= ab1.x; s[1][1] -= ab1.y;
        }
    }
}

// ---------------------------------------------------------------------------
extern "C" void kernel_launch(void* const* d_in, const int* in_sizes, int n_in,
                              void* d_out, int out_size, void* d_ws, size_t ws_size,
                              hipStream_t stream)
{
    const float* I = (const float*)d_in[0];   // image to filter
    const float* R = (const float*)d_in[1];   // guidance image
    float* out = (float*)d_out;

    const long long plane = (long long)H_ * W_;
    const int P_ = (int)(in_sizes[0] / plane);              // 24 planes
    const size_t ab_pb = (size_t)plane * sizeof(__half2);   // 4 MB/plane

    int CH = (int)(ws_size / ab_pb);
    if (CH > P_) CH = P_;
    if (CH < 1) CH = 1;

    __half2* AB = (__half2*)d_ws;

    for (int p0 = 0; p0 < P_; p0 += CH) {
        const int pc = (P_ - p0 < CH) ? (P_ - p0) : CH;
        const long long in_off = (long long)p0 * plane;
        const int nb = NSEG * pc;   // 32*pc => % 8 == 0 for pc multiple of... 32*pc always %8==0

        hipLaunchKernelGGL(gf_ab, dim3(nb), dim3(NT), 0, stream,
                           I, R, in_off, nb, AB);
        hipLaunchKernelGGL(gf_cd, dim3(nb), dim3(NT), 0, stream,
                           AB, R, in_off, nb, out);
    }
}

// Round 7
// 280.534 us; speedup vs baseline: 1.7882x; 1.0048x over previous
//
#include <hip/hip_runtime.h>
#include <hip/hip_fp16.h>

#define H_ 1024
#define W_ 1024
#define RAD 30
#define EPSF 1.3f
#define SH 32            // output rows per block (even; NR=2 batches)
#define NSEG (H_ / SH)   // 32 y-segments
#define NT 512           // 8 waves; 2 px/thread over the full 1024-px row
#define NXCD 8

// padded LDS index: breaks stride bank patterns on prefix reads
__device__ __forceinline__ int padidx(int i) { return i + (i >> 3); }
#define PSZ (W_ + (W_ >> 3) + 1)   // padidx(1024)=1152 -> 1153

__device__ __forceinline__ float wscan(float v, int lane) {
#pragma unroll
    for (int d = 1; d < 64; d <<= 1) {
        const float t = __shfl_up(v, d, 64);
        if (lane >= d) v += t;
    }
    return v;
}

// ---------------------------------------------------------------------------
// gf_ab: block = (plane, 32-row segment), 512 threads, full-width row.
// Vertical sliding sums of {R,I,RI,RR} in registers; 2 rows per barrier
// round: 8 independent wave-scans -> b1 -> 8 LDS prefix arrays -> b2 ->
// box sums + solve a,b for both rows; write packed half2(a,b).
// ---------------------------------------------------------------------------
__global__ __launch_bounds__(NT, 6)
void gf_ab(const float* __restrict__ I, const float* __restrict__ R,
           long long in_off, int nb, __half2* __restrict__ AB)
{
    __shared__ float P[8][PSZ];    // [row*4+field]
    __shared__ float wt[8][8];

    // bijective XCD swizzle (nb % 8 == 0): consecutive segs -> same XCD
    const int q = nb / NXCD;
    const int bid = (int)blockIdx.x;
    const int sbid = (bid % NXCD) * q + bid / NXCD;
    const int seg = sbid % NSEG;
    const int pl  = sbid / NSEG;

    const int tid = threadIdx.x;
    const int lane = tid & 63, wid = tid >> 6;
    const int x0 = tid * 2;
    const int y0 = seg * SH;
    const long long pb = (long long)pl * (long long)(H_ * W_);
    const long long ib = in_off + pb;

    float icx[2];
#pragma unroll
    for (int j = 0; j < 2; ++j) {
        const int x = x0 + j;
        icx[j] = 1.0f / (float)(min(x + RAD, W_ - 1) - max(x - RAD, 0) + 1);
    }

    if (tid == 0) {
#pragma unroll
        for (int f = 0; f < 8; ++f) P[f][0] = 0.0f;   // padidx(0)==0, written once
    }

    float s[4][2];
#pragma unroll
    for (int f = 0; f < 4; ++f) { s[f][0] = 0.0f; s[f][1] = 0.0f; }

    // warm-up rows [y0-RAD, y0+RAD] clipped
    {
        const int wlo = max(0, y0 - RAD), whi = min(H_ - 1, y0 + RAD);
#pragma unroll 4
        for (int yy = wlo; yy <= whi; ++yy) {
            const float2 r2 = *(const float2*)(R + ib + (long long)yy * W_ + x0);
            const float2 i2 = *(const float2*)(I + ib + (long long)yy * W_ + x0);
            s[0][0] += r2.x; s[0][1] += r2.y;
            s[1][0] += i2.x; s[1][1] += i2.y;
            s[2][0] += r2.x * i2.x; s[2][1] += r2.y * i2.y;
            s[3][0] += r2.x * r2.x; s[3][1] += r2.y * r2.y;
        }
    }

    for (int y = y0; y < y0 + SH; y += 2) {
        float ps[8][2], tot[8], wsc[8];

        // ---- snapshot row y scan inputs, slide; snapshot row y+1, slide ----
#pragma unroll
        for (int r = 0; r < 2; ++r) {
            const int yr = y + r;
#pragma unroll
            for (int f = 0; f < 4; ++f) {
                ps[r * 4 + f][0] = s[f][0];
                ps[r * 4 + f][1] = s[f][0] + s[f][1];
            }
            // slide window yr -> yr+1
            const int ya = yr + RAD + 1, yb = yr - RAD;
            if (ya < H_) {
                const float2 r2 = *(const float2*)(R + ib + (long long)ya * W_ + x0);
                const float2 i2 = *(const float2*)(I + ib + (long long)ya * W_ + x0);
                s[0][0] += r2.x; s[0][1] += r2.y;
                s[1][0] += i2.x; s[1][1] += i2.y;
                s[2][0] += r2.x * i2.x; s[2][1] += r2.y * i2.y;
                s[3][0] += r2.x * r2.x; s[3][1] += r2.y * r2.y;
            }
            if (yb >= 0) {
                const float2 r2 = *(const float2*)(R + ib + (long long)yb * W_ + x0);
                const float2 i2 = *(const float2*)(I + ib + (long long)yb * W_ + x0);
                s[0][0] -= r2.x; s[0][1] -= r2.y;
                s[1][0] -= i2.x; s[1][1] -= i2.y;
                s[2][0] -= r2.x * i2.x; s[2][1] -= r2.y * i2.y;
                s[3][0] -= r2.x * r2.x; s[3][1] -= r2.y * r2.y;
            }
        }

        // ---- 8 independent wave scans ----
#pragma unroll
        for (int f = 0; f < 8; ++f) {
            tot[f] = ps[f][1];
            wsc[f] = wscan(tot[f], lane);
            if (lane == 63) wt[f][wid] = wsc[f];
        }
        __syncthreads();   // b1: wt visible

#pragma unroll
        for (int f = 0; f < 8; ++f) {
            float woff = 0.0f;
#pragma unroll
            for (int w = 0; w < 8; ++w)
                if (w < wid) woff += wt[f][w];
            const float ex = woff + wsc[f] - tot[f];  // exclusive prefix at x0
            P[f][padidx(x0 + 1)] = ex + ps[f][0];
            P[f][padidx(x0 + 2)] = ex + ps[f][1];
        }
        __syncthreads();   // b2: P visible

#pragma unroll
        for (int r = 0; r < 2; ++r) {
            const int yr = y + r;
            const float icy = 1.0f / (float)(min(yr + RAD, H_ - 1) - max(yr - RAD, 0) + 1);
            __half2 hv[2];
#pragma unroll
            for (int j = 0; j < 2; ++j) {
                const int x = x0 + j;
                const int hi = padidx(min(x + RAD + 1, W_));
                const int lo = padidx(max(x - RAD, 0));
                const float SR = P[r * 4 + 0][hi] - P[r * 4 + 0][lo];
                const float SI = P[r * 4 + 1][hi] - P[r * 4 + 1][lo];
                const float SP = P[r * 4 + 2][hi] - P[r * 4 + 2][lo];
                const float SQ = P[r * 4 + 3][hi] - P[r * 4 + 3][lo];
                const float invN = icx[j] * icy;
                const float mR = SR * invN, mI = SI * invN;
                const float a = (SP * invN - mR * mI) / (SQ * invN - mR * mR + EPSF);
                const float b = mI - a * mR;
                hv[j] = __floats2half2_rn(a, b);
            }
            const long long ob = pb + (long long)yr * W_ + x0;
            uint2 u;
            u.x = *(const unsigned*)&hv[0];
            u.y = *(const unsigned*)&hv[1];
            *(uint2*)(AB + ob) = u;
        }
        __syncthreads();   // b3: all box reads done before next batch's P writes
    }
}

// ---------------------------------------------------------------------------
// gf_cd: same structure over packed half2 {a,b}; out = mean_a * R + mean_b.
// ---------------------------------------------------------------------------
__global__ __launch_bounds__(NT, 6)
void gf_cd(const __half2* __restrict__ AB, const float* __restrict__ Rimg,
           long long in_off, int nb, float* __restrict__ out)
{
    __shared__ float P[4][PSZ];   // [row*2+field]
    __shared__ float wt[4][8];

    const int q = nb / NXCD;
    const int bid = (int)blockIdx.x;
    const int sbid = (bid % NXCD) * q + bid / NXCD;
    const int seg = sbid % NSEG;
    const int pl  = sbid / NSEG;

    const int tid = threadIdx.x;
    const int lane = tid & 63, wid = tid >> 6;
    const int x0 = tid * 2;
    const int y0 = seg * SH;
    const long long pb = (long long)pl * (long long)(H_ * W_);
    const long long ib = in_off + pb;

    float icx[2];
#pragma unroll
    for (int j = 0; j < 2; ++j) {
        const int x = x0 + j;
        icx[j] = 1.0f / (float)(min(x + RAD, W_ - 1) - max(x - RAD, 0) + 1);
    }

    if (tid == 0) {
#pragma unroll
        for (int f = 0; f < 4; ++f) P[f][0] = 0.0f;
    }

    float s[2][2];
    s[0][0] = s[0][1] = s[1][0] = s[1][1] = 0.0f;

    {
        const int wlo = max(0, y0 - RAD), whi = min(H_ - 1, y0 + RAD);
#pragma unroll 4
        for (int yy = wlo; yy <= whi; ++yy) {
            const uint2 u = *(const uint2*)(AB + pb + (long long)yy * W_ + x0);
            const float2 ab0 = __half22float2(*(const __half2*)&u.x);
            const float2 ab1 = __half22float2(*(const __half2*)&u.y);
            s[0][0] += ab0.x; s[1][0] += ab0.y;
            s[0][1] += ab1.x; s[1][1] += ab1.y;
        }
    }

    for (int y = y0; y < y0 + SH; y += 2) {
        float ps[4][2], tot[4], wsc[4];

#pragma unroll
        for (int r = 0; r < 2; ++r) {
            const int yr = y + r;
#pragma unroll
            for (int f = 0; f < 2; ++f) {
                ps[r * 2 + f][0] = s[f][0];
                ps[r * 2 + f][1] = s[f][0] + s[f][1];
            }
            const int ya = yr + RAD + 1, yb = yr - RAD;
            if (ya < H_) {
                const uint2 u = *(const uint2*)(AB + pb + (long long)ya * W_ + x0);
                const float2 ab0 = __half22float2(*(const __half2*)&u.x);
                const float2 ab1 = __half22float2(*(const __half2*)&u.y);
                s[0][0] += ab0.x; s[1][0] += ab0.y;
                s[0][1] += ab1.x; s[1][1] += ab1.y;
            }
            if (yb >= 0) {
                const uint2 u = *(const uint2*)(AB + pb + (long long)yb * W_ + x0);
                const float2 ab0 = __half22float2(*(const __half2*)&u.x);
                const float2 ab1 = __half22float2(*(const __half2*)&u.y);
                s[0][0] -= ab0.x; s[1][0] -= ab0.y;
                s[0][1] -= ab1.x; s[1][1] -= ab1.y;
            }
        }

#pragma unroll
        for (int f = 0; f < 4; ++f) {
            tot[f] = ps[f][1];
            wsc[f] = wscan(tot[f], lane);
            if (lane == 63) wt[f][wid] = wsc[f];
        }
        __syncthreads();   // b1

#pragma unroll
        for (int f = 0; f < 4; ++f) {
            float woff = 0.0f;
#pragma unroll
            for (int w = 0; w < 8; ++w)
                if (w < wid) woff += wt[f][w];
            const float ex = woff + wsc[f] - tot[f];
            P[f][padidx(x0 + 1)] = ex + ps[f][0];
            P[f][padidx(x0 + 2)] = ex + ps[f][1];
        }
        __syncthreads();   // b2

#pragma unroll
        for (int r = 0; r < 2; ++r) {
            const int yr = y + r;
            const float icy = 1.0f / (float)(min(yr + RAD, H_ - 1) - max(yr - RAD, 0) + 1);
            const long long og = ib + (long long)yr * W_ + x0;
            const float2 r2 = *(const float2*)(Rimg + og);
            float ov[2];
            const float rv[2] = {r2.x, r2.y};
#pragma unroll
            for (int j = 0; j < 2; ++j) {
                const int x = x0 + j;
                const int hi = padidx(min(x + RAD + 1, W_));
                const int lo = padidx(max(x - RAD, 0));
                const float SA = P[r * 2 + 0][hi] - P[r * 2 + 0][lo];
                const float SB = P[r * 2 + 1][hi] - P[r * 2 + 1][lo];
                const float invN = icx[j] * icy;
                ov[j] = (SA * invN) * rv[j] + SB * invN;
            }
            *(float2*)(out + og) = make_float2(ov[0], ov[1]);
        }
        __syncthreads();   // b3
    }
}

// ---------------------------------------------------------------------------
extern "C" void kernel_launch(void* const* d_in, const int* in_sizes, int n_in,
                              void* d_out, int out_size, void* d_ws, size_t ws_size,
                              hipStream_t stream)
{
    const float* I = (const float*)d_in[0];   // image to filter
    const float* R = (const float*)d_in[1];   // guidance image
    float* out = (float*)d_out;

    const long long plane = (long long)H_ * W_;
    const int P_ = (int)(in_sizes[0] / plane);              // 24 planes
    const size_t ab_pb = (size_t)plane * sizeof(__half2);   // 4 MB/plane

    int CH = (int)(ws_size / ab_pb);
    if (CH > P_) CH = P_;
    if (CH < 1) CH = 1;

    __half2* AB = (__half2*)d_ws;

    for (int p0 = 0; p0 < P_; p0 += CH) {
        const int pc = (P_ - p0 < CH) ? (P_ - p0) : CH;
        const long long in_off = (long long)p0 * plane;
        const int nb = NSEG * pc;   // 32*pc

        hipLaunchKernelGGL(gf_ab, dim3(nb), dim3(NT), 0, stream,
                           I, R, in_off, nb, AB);
        hipLaunchKernelGGL(gf_cd, dim3(nb), dim3(NT), 0, stream,
                           AB, R, in_off, nb, out);
    }
}